// Round 7
// baseline (317.921 us; speedup 1.0000x reference)
//
#include <hip/hip_runtime.h>

typedef unsigned short u16;
typedef unsigned int   u32;

typedef __bf16 bf16x8 __attribute__((ext_vector_type(8)));
typedef float  f32x4  __attribute__((ext_vector_type(4)));

__device__ __forceinline__ float bf2f(u16 u){ u32 x = ((u32)u) << 16; return __builtin_bit_cast(float, x); }
__device__ __forceinline__ u16 f2bf(float f){
  u32 u = __builtin_bit_cast(u32, f);
  u32 r = (u + 0x7FFFu + ((u >> 16) & 1u)) >> 16;
  return (u16)r;
}
// pack bf16(a) low16, bf16(b) high16
__device__ __forceinline__ u32 pk2bf(float a, float b){
  u32 ua = __builtin_bit_cast(u32, a) + 0x8000u;
  u32 ub = __builtin_bit_cast(u32, b) + 0x8000u;
  return __builtin_amdgcn_perm(ub, ua, 0x07060302u);
}
// async global->LDS, 16B/lane; lds base wave-uniform, HW adds lane*16
__device__ __forceinline__ void glds16(const void* g, void* l){
  __builtin_amdgcn_global_load_lds((const __attribute__((address_space(1))) void*)g,
                                   (__attribute__((address_space(3))) void*)l, 16, 0, 0);
}
// raw barrier WITHOUT the compiler's vmcnt(0) drain; compiler memory fences on both sides
__device__ __forceinline__ void hard_barrier(){
  asm volatile("" ::: "memory");
  __builtin_amdgcn_s_barrier();
  asm volatile("" ::: "memory");
}

// ---------------- vectorized transpose + cast: f32 [R][C] -> bf16 [C][R], 64x64 tiles ----------------
__global__ __launch_bounds__(256) void transpose_f32_bf16_v(const float* __restrict__ src,
                                                            u16* __restrict__ dst, int R, int C){
  __shared__ u16 T[64 * 72];            // [c][r], stride 72 u16 = 144 B (16B-aligned rows)
  int c0 = blockIdx.x * 64, r0 = blockIdx.y * 64;
  int tr  = threadIdx.x >> 3;           // 0..31
  int tc8 = (threadIdx.x & 7) * 8;
  #pragma unroll
  for (int it = 0; it < 2; ++it){
    int rr = tr + it * 32;
    const float* sp = src + (size_t)(r0 + rr) * C + c0 + tc8;
    float4 f0 = *(const float4*)sp, f1 = *(const float4*)(sp + 4);
    u16 v[8] = { f2bf(f0.x), f2bf(f0.y), f2bf(f0.z), f2bf(f0.w),
                 f2bf(f1.x), f2bf(f1.y), f2bf(f1.z), f2bf(f1.w) };
    #pragma unroll
    for (int j = 0; j < 8; ++j) T[(tc8 + j) * 72 + rr] = v[j];
  }
  __syncthreads();
  int tcw = threadIdx.x >> 3;
  int tr8 = (threadIdx.x & 7) * 8;
  #pragma unroll
  for (int it = 0; it < 2; ++it){
    int cc = tcw + it * 32;
    *(uint4*)(dst + (size_t)(c0 + cc) * R + r0 + tr8) = *(const uint4*)&T[cc * 72 + tr8];
  }
}

// ---------------- f32 -> bf16 bulk convert (8 elems/thread) ----------------
__global__ __launch_bounds__(256) void cvt_f32_bf16(const float* __restrict__ src,
                                                    u16* __restrict__ dst){
  size_t i = ((size_t)blockIdx.x * 256 + threadIdx.x) * 8;
  const float4* a4 = (const float4*)(src + i);
  float4 f0 = a4[0], f1 = a4[1];
  u32 w[4] = { pk2bf(f0.x, f0.y), pk2bf(f0.z, f0.w), pk2bf(f1.x, f1.y), pk2bf(f1.z, f1.w) };
  *(uint4*)(dst + i) = *(const uint4*)w;
}

// ---------------- split-K projection: P[s][m][0..191] = x[m][ks] @ [wk;wp][ks] ----------------
__global__ __launch_bounds__(256) void proj_splitk(const float* __restrict__ X,
    const u16* __restrict__ BT, float* __restrict__ P){
  constexpr int Kf = 7168;
  const int s = blockIdx.x, m0 = blockIdx.y * 64;
  const int kbase = s * 448;
  __shared__ u16 As[2 * 64 * 36];      // [kc][64][36] padded (VALU-packed stores)
  __shared__ u16 Bs[2 * 192 * 32];     // [kc][192][32] unpadded (glds)
  const int tid = threadIdx.x, wave = tid >> 6, lane = tid & 63;
  const int row = lane & 15, quad = lane >> 4;
  const int wm = (wave & 1) * 32, wn = (wave >> 1) * 96;

  const f32x4 zero = {0.f, 0.f, 0.f, 0.f};
  f32x4 acc[2][6];
  #pragma unroll
  for (int mt = 0; mt < 2; ++mt)
    #pragma unroll
    for (int nt = 0; nt < 6; ++nt) acc[mt][nt] = zero;

  for (int kb = 0; kb < 7; ++kb) {
    int k0 = kbase + kb * 64;
    #pragma unroll
    for (int c = 0; c < 6; ++c) {
      int chunk = wave * 6 + c;
      int kc = chunk / 12, rem = chunk % 12;
      int r = rem * 16 + (lane >> 2), col = (lane & 3) * 8;
      glds16(BT + (size_t)r * Kf + k0 + kc * 32 + col, (void*)&Bs[chunk * 512]);
    }
    #pragma unroll
    for (int c = 0; c < 2; ++c) {
      int idx = tid + c * 256;
      int r = idx >> 3, kf = (idx & 7) * 8;
      const float4* ap = (const float4*)(X + (size_t)(m0 + r) * Kf + k0 + kf);
      float4 f0 = ap[0], f1 = ap[1];
      u32 w[4] = { pk2bf(f0.x, f0.y), pk2bf(f0.z, f0.w), pk2bf(f1.x, f1.y), pk2bf(f1.z, f1.w) };
      *(uint4*)&As[(kf >> 5) * 2304 + r * 36 + (kf & 31)] = *(const uint4*)w;
    }
    __syncthreads();
    #pragma unroll
    for (int ks = 0; ks < 2; ++ks) {
      bf16x8 af[2], bfr[6];
      #pragma unroll
      for (int mt = 0; mt < 2; ++mt) af[mt] = *(const bf16x8*)&As[ks * 2304 + (wm + mt * 16 + row) * 36 + quad * 8];
      #pragma unroll
      for (int nt = 0; nt < 6; ++nt) bfr[nt] = *(const bf16x8*)&Bs[ks * 6144 + (wn + nt * 16 + row) * 32 + quad * 8];
      #pragma unroll
      for (int mt = 0; mt < 2; ++mt)
        #pragma unroll
        for (int nt = 0; nt < 6; ++nt)
          acc[mt][nt] = __builtin_amdgcn_mfma_f32_16x16x32_bf16(af[mt], bfr[nt], acc[mt][nt], 0, 0, 0);
    }
    __syncthreads();
  }
  #pragma unroll
  for (int mt = 0; mt < 2; ++mt)
    #pragma unroll
    for (int nt = 0; nt < 6; ++nt)
      #pragma unroll
      for (int r = 0; r < 4; ++r) {
        int rr = m0 + wm + mt * 16 + quad * 4 + r;
        int cc = wn + nt * 16 + row;
        P[((size_t)s * 2048 + rr) * 192 + cc] = acc[mt][nt][r];
      }
}

// ---------------- reduce 16 partials + LayerNorm + RoPE -> Kbf (bf16), WT (f32, [h][tok]) ----------------
__global__ __launch_bounds__(64) void reduce_lnrope(const float* __restrict__ P,
    const float* __restrict__ cosb, const float* __restrict__ sinb,
    const float* __restrict__ gam, const float* __restrict__ bet,
    u16* __restrict__ Kout, float* __restrict__ WoutT){
  int tok = blockIdx.x, lane = threadIdx.x;
  float v0 = 0.f, v1 = 0.f, w = 0.f;
  #pragma unroll
  for (int s = 0; s < 16; ++s) {
    const float* p = P + ((size_t)s * 2048 + tok) * 192;
    v0 += p[2 * lane]; v1 += p[2 * lane + 1]; w += p[128 + lane];
  }
  WoutT[(size_t)lane * 2048 + tok] = w;     // transposed: [h][tok]
  float sm = v0 + v1;
  #pragma unroll
  for (int m = 1; m < 64; m <<= 1) sm += __shfl_xor(sm, m);
  float mu = sm * (1.f / 128.f);
  float d0 = v0 - mu, d1 = v1 - mu;
  float sq = d0 * d0 + d1 * d1;
  #pragma unroll
  for (int m = 1; m < 64; m <<= 1) sq += __shfl_xor(sq, m);
  float rs = rsqrtf(sq * (1.f / 128.f) + 1e-6f);
  float kn0 = d0 * rs * gam[2 * lane]     + bet[2 * lane];
  float kn1 = d1 * rs * gam[2 * lane + 1] + bet[2 * lane + 1];
  float o0 = kn0, o1 = kn1;
  if (lane < 32) {
    float c  = cosb[tok * 64 + 2 * lane];
    float sn = sinb[tok * 64 + 2 * lane];
    o0 = kn0 * c - kn1 * sn;
    o1 = kn1 * c + kn0 * sn;
  }
  Kout[tok * 128 + 2 * lane]     = f2bf(o0);
  Kout[tok * 128 + 2 * lane + 1] = f2bf(o1);
}

// ---------------- legacy Q-GEMM (fallback path when workspace is small) ----------------
template<bool AGLDS>
__global__ __launch_bounds__(256) void qgemm(const void* __restrict__ Aptr,
    const u16* __restrict__ BT, const float* __restrict__ cosb,
    const float* __restrict__ sinb, u16* __restrict__ Qout){
  constexpr int K = 1536, N = 8192;
  __shared__ u16 As[2 * 128 * 32];   // [kc][128][32] unpadded (glds / packed stores)
  __shared__ u16 Bs[2 * 128 * 32];
  const int tid = threadIdx.x, wave = tid >> 6, lane = tid & 63;
  const int row = lane & 15, quad = lane >> 4;
  const int wm = (wave >> 1) * 64, wn = (wave & 1) * 64;
  const int m0 = blockIdx.y * 128, n0 = blockIdx.x * 128;

  const f32x4 zero = {0.f, 0.f, 0.f, 0.f};
  f32x4 acc[4][4];
  #pragma unroll
  for (int mt = 0; mt < 4; ++mt)
    #pragma unroll
    for (int nt = 0; nt < 4; ++nt) acc[mt][nt] = zero;

  for (int k0 = 0; k0 < K; k0 += 64) {
    #pragma unroll
    for (int c = 0; c < 4; ++c) {            // B: 16 chunks (1024B), 4/wave
      int chunk = wave * 4 + c;
      int kc = chunk >> 3, rg = chunk & 7;
      int r = rg * 16 + (lane >> 2), col = kc * 32 + (lane & 3) * 8;
      glds16(BT + (size_t)(n0 + r) * K + k0 + col, (void*)&Bs[chunk * 512]);
    }
    if (AGLDS) {
      #pragma unroll
      for (int c = 0; c < 4; ++c) {
        int chunk = wave * 4 + c;
        int kc = chunk >> 3, rg = chunk & 7;
        int r = rg * 16 + (lane >> 2), col = kc * 32 + (lane & 3) * 8;
        glds16((const u16*)Aptr + (size_t)(m0 + r) * K + k0 + col, (void*)&As[chunk * 512]);
      }
    } else {
      #pragma unroll
      for (int c = 0; c < 4; ++c) {          // A: f32 load + pack, 128x64
        int idx = tid + c * 256;
        int r = idx >> 3, kf = (idx & 7) * 8;
        const float4* ap = (const float4*)((const float*)Aptr + (size_t)(m0 + r) * K + k0 + kf);
        float4 f0 = ap[0], f1 = ap[1];
        u32 w[4] = { pk2bf(f0.x, f0.y), pk2bf(f0.z, f0.w), pk2bf(f1.x, f1.y), pk2bf(f1.z, f1.w) };
        *(uint4*)&As[(kf >> 5) * 4096 + r * 32 + (kf & 31)] = *(const uint4*)w;
      }
    }
    __syncthreads();
    #pragma unroll
    for (int kk = 0; kk < 2; ++kk) {
      bf16x8 af[4], bfr[4];
      #pragma unroll
      for (int mt = 0; mt < 4; ++mt) af[mt]  = *(const bf16x8*)&As[kk * 4096 + (wm + mt * 16 + row) * 32 + quad * 8];
      #pragma unroll
      for (int nt = 0; nt < 4; ++nt) bfr[nt] = *(const bf16x8*)&Bs[kk * 4096 + (wn + nt * 16 + row) * 32 + quad * 8];
      #pragma unroll
      for (int mt = 0; mt < 4; ++mt)
        #pragma unroll
        for (int nt = 0; nt < 4; ++nt)
          acc[mt][nt] = __builtin_amdgcn_mfma_f32_16x16x32_bf16(af[mt], bfr[nt], acc[mt][nt], 0, 0, 0);
    }
    __syncthreads();
  }

  const bool roped = (wn == 0);
  #pragma unroll
  for (int mt = 0; mt < 4; ++mt)
    #pragma unroll
    for (int nt = 0; nt < 4; ++nt)
      #pragma unroll
      for (int r = 0; r < 4; ++r) {
        int rr = m0 + wm + mt * 16 + quad * 4 + r;
        int cc = n0 + wn + nt * 16 + row;
        float v = acc[mt][nt][r];
        float o = v;
        if (roped) {
          int hd = (wn + nt * 16 + row) & 127;
          float c = cosb[rr * 64 + hd];
          float s = sinb[rr * 64 + hd];
          float vo = __shfl_xor(v, 1);
          o = (cc & 1) ? (v * c + vo * s) : (v * c - vo * s);
        }
        Qout[(size_t)rr * N + cc] = f2bf(o);
      }
}

// ---------------- Q-GEMM v7: 128x128 tile, v4 counted-vmcnt pipeline, 2 blocks/CU ----------------
// Occupancy experiment (m114 mechanism): v4-v6 at 128 KiB LDS = 1 block/CU -> every barrier
// stalls the whole CU; 3 rounds of intra-block scheduling moved <=10%. Shrink to 128x128 tile,
// 4 waves (2x2, wave tile 64x64), 64 KiB LDS -> 2 blocks/CU: block A's MFMA overlaps block B's
// barrier/lgkm stalls. Pipeline ledger identical to v4 (per-point = 4 glds/thread):
//   prologue: H0(0),H1(0),H0(1) = 12 in flight
//   P1(kk0): vmcnt(8) [4 last]; barrier; read kk0; stage H1(t+1); lgkm0; setprio MFMA x16
//   P2(kk1): vmcnt(8) [0 last]; barrier; read kk1; stage H0(t+2); lgkm0; setprio MFMA x16
// Swizzle identical to v4 (64-B rows, row bits 1..2 into byte bits 5..4, involution both sides).
// Grid 1024 flat, bijective XCD swizzle: XCD k owns n-panels [8k..8k+8) x all 16 m-panels
// (B-slice 3 MB fits 4 MB per-XCD L2).
__global__ __launch_bounds__(256, 2) void qgemm128v7(const u16* __restrict__ A,
    const u16* __restrict__ BT, const float* __restrict__ cosb,
    const float* __restrict__ sinb, u16* __restrict__ Qout){
  constexpr int K = 1536, N = 8192, NT = 24;
  __shared__ __align__(16) u16 As[2 * 2 * 128 * 32];   // 32 KiB: [d][kk][row][32]
  __shared__ __align__(16) u16 Bs[2 * 2 * 128 * 32];   // 32 KiB
  const int tid = threadIdx.x, wave = tid >> 6, lane = tid & 63;
  const int lrow = lane & 15, quad = lane >> 4;
  const int wr = wave >> 1, wc = wave & 1;             // 2x2 waves; wave tile 64x64

  const int flat = blockIdx.x;                          // 1024 blocks
  const int xcd = flat & 7, idx = flat >> 3;            // bijective XCD remap
  const int m_t = idx & 15, n_t = xcd * 8 + (idx >> 4);
  const int m0 = m_t * 128, n0 = n_t * 128;

  // staging sources (per-lane, pre-swizzled logical columns); row = tid>>2 (0..63) per half
  const int scolb = ((tid & 3) << 4) ^ (((tid >> 3) & 1) << 5) ^ (((tid >> 4) & 1) << 4);
  const int scole = scolb >> 1;
  const int srow  = tid >> 2;
  const u16* sa0 = A  + (size_t)(m0 +      srow) * K + scole;
  const u16* sa1 = A  + (size_t)(m0 + 64 + srow) * K + scole;
  const u16* sb0 = BT + (size_t)(n0 +      srow) * K + scole;
  const u16* sb1 = BT + (size_t)(n0 + 64 + srow) * K + scole;

  auto stagept = [&](int t, int h){                     // one half-point: 4 glds16/thread
    const int off = t * 64 + h * 32;
    u16* la = (u16*)As + (size_t)((t & 1) * 2 + h) * 4096 + wave * 512;  // wave-uniform base
    u16* lb = (u16*)Bs + (size_t)((t & 1) * 2 + h) * 4096 + wave * 512;
    glds16(sa0 + off, (void*)la);
    glds16(sa1 + off, (void*)(la + 2048));              // rows 64..127
    glds16(sb0 + off, (void*)lb);
    glds16(sb1 + off, (void*)(lb + 2048));
  };

  // fragment read offsets (bytes within one [128][32] region, row stride 64 B)
  const int swzr = ((lrow & 2) << 4) | ((lrow & 4) << 2);
  const int aoff = (wr * 64 + lrow) * 64 + ((quad * 16) ^ swzr);   // + mt*1024
  const int boff = (wc * 64 + lrow) * 64 + ((quad * 16) ^ swzr);   // + nt*1024

  const f32x4 zero = {0.f, 0.f, 0.f, 0.f};
  f32x4 acc[4][4];
  #pragma unroll
  for (int mt = 0; mt < 4; ++mt)
    #pragma unroll
    for (int nt = 0; nt < 4; ++nt) acc[mt][nt] = zero;

  // prologue: H0(0), H1(0), H0(1) in flight (12 loads/wave)
  stagept(0, 0); stagept(0, 1); stagept(1, 0);

  for (int t = 0; t < NT; ++t) {
    const int d = t & 1;
    const bool last = (t == NT - 1);
    const char* A0 = (const char*)As + d * 16384;       // [d][kk=0] region (8192 B each)
    const char* B0 = (const char*)Bs + d * 16384;
    const char* A1 = A0 + 8192;
    const char* B1 = B0 + 8192;
    bf16x8 af[4], bfr[4];

    // -------- P1: kk=0
    if (!last) { asm volatile("s_waitcnt vmcnt(8)" ::: "memory"); }
    else       { asm volatile("s_waitcnt vmcnt(4)" ::: "memory"); }
    hard_barrier();
    #pragma unroll
    for (int j = 0; j < 4; ++j) af[j]  = *(const bf16x8*)(A0 + aoff + j * 1024);
    #pragma unroll
    for (int j = 0; j < 4; ++j) bfr[j] = *(const bf16x8*)(B0 + boff + j * 1024);
    if (t + 1 < NT) stagept(t + 1, 1);
    asm volatile("s_waitcnt lgkmcnt(0)" ::: "memory");
    __builtin_amdgcn_sched_barrier(0);
    __builtin_amdgcn_s_setprio(1);
    #pragma unroll
    for (int j = 0; j < 4; ++j)
      #pragma unroll
      for (int nt = 0; nt < 4; ++nt)
        acc[j][nt] = __builtin_amdgcn_mfma_f32_16x16x32_bf16(af[j], bfr[nt], acc[j][nt], 0, 0, 0);
    __builtin_amdgcn_s_setprio(0);

    // -------- P2: kk=1
    if (!last) { asm volatile("s_waitcnt vmcnt(8)" ::: "memory"); }
    else       { asm volatile("s_waitcnt vmcnt(0)" ::: "memory"); }
    hard_barrier();
    #pragma unroll
    for (int j = 0; j < 4; ++j) af[j]  = *(const bf16x8*)(A1 + aoff + j * 1024);
    #pragma unroll
    for (int j = 0; j < 4; ++j) bfr[j] = *(const bf16x8*)(B1 + boff + j * 1024);
    if (t + 2 < NT) stagept(t + 2, 0);
    asm volatile("s_waitcnt lgkmcnt(0)" ::: "memory");
    __builtin_amdgcn_sched_barrier(0);
    __builtin_amdgcn_s_setprio(1);
    #pragma unroll
    for (int j = 0; j < 4; ++j)
      #pragma unroll
      for (int nt = 0; nt < 4; ++nt)
        acc[j][nt] = __builtin_amdgcn_mfma_f32_16x16x32_bf16(af[j], bfr[nt], acc[j][nt], 0, 0, 0);
    __builtin_amdgcn_s_setprio(0);
  }

  // epilogue: fused RoPE on cols with (cc&127) < 64  <=>  wc == 0
  const bool roped = (wc == 0);
  #pragma unroll
  for (int mt = 0; mt < 4; ++mt)
    #pragma unroll
    for (int nt = 0; nt < 4; ++nt)
      #pragma unroll
      for (int r = 0; r < 4; ++r) {
        int rr = m0 + wr * 64 + mt * 16 + quad * 4 + r;
        int cc = n0 + wc * 64 + nt * 16 + lrow;
        float v = acc[mt][nt][r];
        float o = v;
        if (roped) {
          int hd = nt * 16 + lrow;                 // < 64
          float c = cosb[rr * 64 + hd];
          float s = sinb[rr * 64 + hd];
          float vo = __shfl_xor(v, 1);
          o = (cc & 1) ? (v * c + vo * s) : (v * c - vo * s);
        }
        Qout[(size_t)rr * N + cc] = f2bf(o);
      }
}

// ---------------- fused scores: double-buffered Q stage, ONE barrier per 2-head pair ----------------
__global__ __launch_bounds__(256) void attn_kernel(const u16* __restrict__ Q,
    const u16* __restrict__ Kb, const float* __restrict__ WT, float* __restrict__ out){
  int blk = blockIdx.x;                       // 512 blocks
  int x = blk & 7, kt = (blk >> 3) & 7, hs = (blk >> 6) & 1, g4 = (blk >> 7) & 3;
  int p = x + 8 * g4;                         // 0..31
  int b = p >> 4, qt = p & 15;
  int q0 = qt * 64, k0 = kt * 128;

  const int tid = threadIdx.x, wave = tid >> 6, lane = tid & 63;
  const int row = lane & 15, quad = lane >> 4;
  const int wm = (wave >> 1) * 32;            // q offset (0/32)
  const int wn = (wave & 1) * 64;             // k offset (0/64)

  __shared__ u16 Sh[2][16384];                // 2 x 32 KB buffers; Sh[0] first holds the K tile
  __shared__ float Ws[32 * 64];               // 8 KB: [h_local][q_local]

  // stage K tile 128x128 into Sh[0] as [r][128]
  #pragma unroll
  for (int c = 0; c < 8; ++c) {
    int g = wave * 8 + c;
    int rr = g * 4 + (lane >> 4), col = (lane & 15) * 8;
    glds16(Kb + (size_t)(b * 1024 + k0 + rr) * 128 + col, (void*)&Sh[0][g * 512]);
  }
  {
    int hl = tid >> 3, qq = (tid & 7) * 8;
    const float* srcw = WT + (size_t)(hs * 32 + hl) * 2048 + b * 1024 + q0 + qq;
    *(float4*)&Ws[hl * 64 + qq]     = *(const float4*)srcw;
    *(float4*)&Ws[hl * 64 + qq + 4] = *(const float4*)(srcw + 4);
  }
  __syncthreads();

  bf16x8 bfr[4][4];                           // h-invariant K fragments (read once)
  #pragma unroll
  for (int ks = 0; ks < 4; ++ks)
    #pragma unroll
    for (int nt = 0; nt < 4; ++nt)
      bfr[ks][nt] = *(const bf16x8*)&Sh[0][(wn + nt * 16 + row) * 128 + ks * 32 + quad * 8];
  __syncthreads();                            // all waves done reading K before Q overwrites Sh[0]

  const u16* Qbase = Q + (size_t)(b * 1024 + q0) * 8192;
  auto stage = [&](int half, int pairIdx){    // stage 2 heads (32 KB): 32 chunks, 8/wave
    int h0 = hs * 32 + pairIdx * 2;
    #pragma unroll
    for (int c = 0; c < 8; ++c) {
      int g = wave * 8 + c;
      int hsub = g >> 4, rem = g & 15;
      int kc = rem >> 2, rg = rem & 3;
      glds16(Qbase + (size_t)(rg * 16 + (lane >> 2)) * 8192 + (h0 + hsub) * 128 + kc * 32 + (lane & 3) * 8,
             (void*)&Sh[half][hsub * 8192 + rem * 512]);
    }
  };

  const f32x4 zero = {0.f, 0.f, 0.f, 0.f};
  f32x4 sacc[2][4];
  #pragma unroll
  for (int mt = 0; mt < 2; ++mt)
    #pragma unroll
    for (int nt = 0; nt < 4; ++nt) sacc[mt][nt] = zero;

  stage(0, 0);                                // prefetch pair 0
  for (int hp = 0; hp < 16; ++hp) {
    __syncthreads();                          // drains pair hp's glds (in shadow for hp>=1)
    if (hp < 15) stage((hp + 1) & 1, hp + 1); // prefetch next pair before compute
    const u16* S = Sh[hp & 1];
    #pragma unroll
    for (int hsub = 0; hsub < 2; ++hsub) {
      f32x4 lg[2][4];
      #pragma unroll
      for (int mt = 0; mt < 2; ++mt)
        #pragma unroll
        for (int nt = 0; nt < 4; ++nt) lg[mt][nt] = zero;
      #pragma unroll
      for (int ks = 0; ks < 4; ++ks) {
        bf16x8 af0 = *(const bf16x8*)&S[hsub * 8192 + ks * 2048 + (wm +      row) * 32 + quad * 8];
        bf16x8 af1 = *(const bf16x8*)&S[hsub * 8192 + ks * 2048 + (wm + 16 + row) * 32 + quad * 8];
        #pragma unroll
        for (int nt = 0; nt < 4; ++nt) {
          lg[0][nt] = __builtin_amdgcn_mfma_f32_16x16x32_bf16(af0, bfr[ks][nt], lg[0][nt], 0, 0, 0);
          lg[1][nt] = __builtin_amdgcn_mfma_f32_16x16x32_bf16(af1, bfr[ks][nt], lg[1][nt], 0, 0, 0);
        }
      }
      int hl = hp * 2 + hsub;
      f32x4 w0 = *(const f32x4*)&Ws[hl * 64 + wm +      quad * 4];
      f32x4 w1 = *(const f32x4*)&Ws[hl * 64 + wm + 16 + quad * 4];
      #pragma unroll
      for (int nt = 0; nt < 4; ++nt)
        #pragma unroll
        for (int r = 0; r < 4; ++r) {
          sacc[0][nt][r] += w0[r] * fmaxf(lg[0][nt][r], 0.f);
          sacc[1][nt][r] += w1[r] * fmaxf(lg[1][nt][r], 0.f);
        }
    }
  }

  const float scale = 0.088388347648318447f;  // 128^-0.5
  #pragma unroll
  for (int mt = 0; mt < 2; ++mt)
    #pragma unroll
    for (int nt = 0; nt < 4; ++nt)
      #pragma unroll
      for (int r = 0; r < 4; ++r) {
        int qq = q0 + wm + mt * 16 + quad * 4 + r;
        int kk = k0 + wn + nt * 16 + row;
        unsafeAtomicAdd(&out[((size_t)b << 20) + (size_t)qq * 1024 + kk], scale * sacc[mt][nt][r]);
      }
}

extern "C" void kernel_launch(void* const* d_in, const int* in_sizes, int n_in,
                              void* d_out, int out_size, void* d_ws, size_t ws_size,
                              hipStream_t stream) {
  const float* x    = (const float*)d_in[0];   // [2048][7168]
  const float* qr   = (const float*)d_in[1];   // [2048][1536]
  const float* cosb = (const float*)d_in[2];   // [2048][64]
  const float* sinb = (const float*)d_in[3];   // [2048][64]
  const float* wq   = (const float*)d_in[4];   // [1536][8192]
  const float* wk   = (const float*)d_in[5];   // [7168][128]
  const float* wp   = (const float*)d_in[6];   // [7168][64]
  const float* gam  = (const float*)d_in[7];   // [128]
  const float* bet  = (const float*)d_in[8];   // [128]
  float* out = (float*)d_out;                  // [2][1024][1024] f32

  char* ws = (char*)d_ws;
  float* P    = (float*)(ws + 0);          // [16][2048][192] f32 = 25,165,824 B (proj phase)
  u16*   wqT  = (u16*)(ws + 0);            // [8192][1536] bf16 (after reduce; same region)
  u16*   wkwpT= (u16*)(ws + 25165824);     // [192][7168] bf16 = 2,752,512 B
  float* WT   = (float*)(ws + 27918336);   // [64][2048] f32 = 524,288 B (transposed W)
  u16*   Kbf  = (u16*)(ws + 28442624);     // [2048][128] bf16 = 524,288 B
  u16*   Qbf  = (u16*)(ws + 28966912);     // [2048][8192] bf16 = 33,554,432 B -> 62,521,344
  const size_t QRB_OFF = 62521344;
  u16*   qrb  = (u16*)(ws + QRB_OFF);      // [2048][1536] bf16 = 6,291,456 B -> 68,812,800
  const bool big_ws = (ws_size >= (size_t)68812800);

  (void)in_sizes; (void)n_in;

  hipMemsetAsync(d_out, 0, (size_t)out_size * 4, stream);

  transpose_f32_bf16_v<<<dim3(2, 112), 256, 0, stream>>>(wk, wkwpT,              7168, 128);
  transpose_f32_bf16_v<<<dim3(1, 112), 256, 0, stream>>>(wp, wkwpT + 128 * 7168, 7168, 64);

  proj_splitk<<<dim3(16, 32), 256, 0, stream>>>(x, wkwpT, P);
  reduce_lnrope<<<2048, 64, 0, stream>>>(P, cosb, sinb, gam, bet, Kbf, WT);

  transpose_f32_bf16_v<<<dim3(128, 24), 256, 0, stream>>>(wq, wqT, 1536, 8192);

  if (big_ws) {
    cvt_f32_bf16<<<1536, 256, 0, stream>>>(qr, qrb);
    qgemm128v7<<<1024, 256, 0, stream>>>(qrb, wqT, cosb, sinb, Qbf);
  } else {
    qgemm<false><<<dim3(64, 16), 256, 0, stream>>>(qr, wqT, cosb, sinb, Qbf);
  }

  attn_kernel<<<512, 256, 0, stream>>>(Qbf, Kbf, WT, out);
}

// Round 8
// 304.555 us; speedup vs baseline: 1.0439x; 1.0439x over previous
//
#include <hip/hip_runtime.h>

typedef unsigned short u16;
typedef unsigned int   u32;

typedef __bf16 bf16x8 __attribute__((ext_vector_type(8)));
typedef float  f32x4  __attribute__((ext_vector_type(4)));

__device__ __forceinline__ float bf2f(u16 u){ u32 x = ((u32)u) << 16; return __builtin_bit_cast(float, x); }
__device__ __forceinline__ u16 f2bf(float f){
  u32 u = __builtin_bit_cast(u32, f);
  u32 r = (u + 0x7FFFu + ((u >> 16) & 1u)) >> 16;
  return (u16)r;
}
// pack bf16(a) low16, bf16(b) high16
__device__ __forceinline__ u32 pk2bf(float a, float b){
  u32 ua = __builtin_bit_cast(u32, a) + 0x8000u;
  u32 ub = __builtin_bit_cast(u32, b) + 0x8000u;
  return __builtin_amdgcn_perm(ub, ua, 0x07060302u);
}
// async global->LDS, 16B/lane; lds base wave-uniform, HW adds lane*16
__device__ __forceinline__ void glds16(const void* g, void* l){
  __builtin_amdgcn_global_load_lds((const __attribute__((address_space(1))) void*)g,
                                   (__attribute__((address_space(3))) void*)l, 16, 0, 0);
}
// raw barrier WITHOUT the compiler's vmcnt(0) drain; compiler memory fences on both sides
__device__ __forceinline__ void hard_barrier(){
  asm volatile("" ::: "memory");
  __builtin_amdgcn_s_barrier();
  asm volatile("" ::: "memory");
}

// ---------------- vectorized transpose + cast: f32 [R][C] -> bf16 [C][R], 64x64 tiles ----------------
__global__ __launch_bounds__(256) void transpose_f32_bf16_v(const float* __restrict__ src,
                                                            u16* __restrict__ dst, int R, int C){
  __shared__ u16 T[64 * 72];            // [c][r], stride 72 u16 = 144 B (16B-aligned rows)
  int c0 = blockIdx.x * 64, r0 = blockIdx.y * 64;
  int tr  = threadIdx.x >> 3;           // 0..31
  int tc8 = (threadIdx.x & 7) * 8;
  #pragma unroll
  for (int it = 0; it < 2; ++it){
    int rr = tr + it * 32;
    const float* sp = src + (size_t)(r0 + rr) * C + c0 + tc8;
    float4 f0 = *(const float4*)sp, f1 = *(const float4*)(sp + 4);
    u16 v[8] = { f2bf(f0.x), f2bf(f0.y), f2bf(f0.z), f2bf(f0.w),
                 f2bf(f1.x), f2bf(f1.y), f2bf(f1.z), f2bf(f1.w) };
    #pragma unroll
    for (int j = 0; j < 8; ++j) T[(tc8 + j) * 72 + rr] = v[j];
  }
  __syncthreads();
  int tcw = threadIdx.x >> 3;
  int tr8 = (threadIdx.x & 7) * 8;
  #pragma unroll
  for (int it = 0; it < 2; ++it){
    int cc = tcw + it * 32;
    *(uint4*)(dst + (size_t)(c0 + cc) * R + r0 + tr8) = *(const uint4*)&T[cc * 72 + tr8];
  }
}

// ---------------- f32 -> bf16 bulk convert (8 elems/thread) ----------------
__global__ __launch_bounds__(256) void cvt_f32_bf16(const float* __restrict__ src,
                                                    u16* __restrict__ dst){
  size_t i = ((size_t)blockIdx.x * 256 + threadIdx.x) * 8;
  const float4* a4 = (const float4*)(src + i);
  float4 f0 = a4[0], f1 = a4[1];
  u32 w[4] = { pk2bf(f0.x, f0.y), pk2bf(f0.z, f0.w), pk2bf(f1.x, f1.y), pk2bf(f1.z, f1.w) };
  *(uint4*)(dst + i) = *(const uint4*)w;
}

// ---------------- split-K projection: P[s][m][0..191] = x[m][ks] @ [wk;wp][ks] ----------------
__global__ __launch_bounds__(256) void proj_splitk(const float* __restrict__ X,
    const u16* __restrict__ BT, float* __restrict__ P){
  constexpr int Kf = 7168;
  const int s = blockIdx.x, m0 = blockIdx.y * 64;
  const int kbase = s * 448;
  __shared__ u16 As[2 * 64 * 36];      // [kc][64][36] padded (VALU-packed stores)
  __shared__ u16 Bs[2 * 192 * 32];     // [kc][192][32] unpadded (glds)
  const int tid = threadIdx.x, wave = tid >> 6, lane = tid & 63;
  const int row = lane & 15, quad = lane >> 4;
  const int wm = (wave & 1) * 32, wn = (wave >> 1) * 96;

  const f32x4 zero = {0.f, 0.f, 0.f, 0.f};
  f32x4 acc[2][6];
  #pragma unroll
  for (int mt = 0; mt < 2; ++mt)
    #pragma unroll
    for (int nt = 0; nt < 6; ++nt) acc[mt][nt] = zero;

  for (int kb = 0; kb < 7; ++kb) {
    int k0 = kbase + kb * 64;
    #pragma unroll
    for (int c = 0; c < 6; ++c) {
      int chunk = wave * 6 + c;
      int kc = chunk / 12, rem = chunk % 12;
      int r = rem * 16 + (lane >> 2), col = (lane & 3) * 8;
      glds16(BT + (size_t)r * Kf + k0 + kc * 32 + col, (void*)&Bs[chunk * 512]);
    }
    #pragma unroll
    for (int c = 0; c < 2; ++c) {
      int idx = tid + c * 256;
      int r = idx >> 3, kf = (idx & 7) * 8;
      const float4* ap = (const float4*)(X + (size_t)(m0 + r) * Kf + k0 + kf);
      float4 f0 = ap[0], f1 = ap[1];
      u32 w[4] = { pk2bf(f0.x, f0.y), pk2bf(f0.z, f0.w), pk2bf(f1.x, f1.y), pk2bf(f1.z, f1.w) };
      *(uint4*)&As[(kf >> 5) * 2304 + r * 36 + (kf & 31)] = *(const uint4*)w;
    }
    __syncthreads();
    #pragma unroll
    for (int ks = 0; ks < 2; ++ks) {
      bf16x8 af[2], bfr[6];
      #pragma unroll
      for (int mt = 0; mt < 2; ++mt) af[mt] = *(const bf16x8*)&As[ks * 2304 + (wm + mt * 16 + row) * 36 + quad * 8];
      #pragma unroll
      for (int nt = 0; nt < 6; ++nt) bfr[nt] = *(const bf16x8*)&Bs[ks * 6144 + (wn + nt * 16 + row) * 32 + quad * 8];
      #pragma unroll
      for (int mt = 0; mt < 2; ++mt)
        #pragma unroll
        for (int nt = 0; nt < 6; ++nt)
          acc[mt][nt] = __builtin_amdgcn_mfma_f32_16x16x32_bf16(af[mt], bfr[nt], acc[mt][nt], 0, 0, 0);
    }
    __syncthreads();
  }
  #pragma unroll
  for (int mt = 0; mt < 2; ++mt)
    #pragma unroll
    for (int nt = 0; nt < 6; ++nt)
      #pragma unroll
      for (int r = 0; r < 4; ++r) {
        int rr = m0 + wm + mt * 16 + quad * 4 + r;
        int cc = wn + nt * 16 + row;
        P[((size_t)s * 2048 + rr) * 192 + cc] = acc[mt][nt][r];
      }
}

// ---------------- reduce 16 partials + LayerNorm + RoPE -> Kbf (bf16), WT (f32, [h][tok]) ----------------
__global__ __launch_bounds__(64) void reduce_lnrope(const float* __restrict__ P,
    const float* __restrict__ cosb, const float* __restrict__ sinb,
    const float* __restrict__ gam, const float* __restrict__ bet,
    u16* __restrict__ Kout, float* __restrict__ WoutT){
  int tok = blockIdx.x, lane = threadIdx.x;
  float v0 = 0.f, v1 = 0.f, w = 0.f;
  #pragma unroll
  for (int s = 0; s < 16; ++s) {
    const float* p = P + ((size_t)s * 2048 + tok) * 192;
    v0 += p[2 * lane]; v1 += p[2 * lane + 1]; w += p[128 + lane];
  }
  WoutT[(size_t)lane * 2048 + tok] = w;     // transposed: [h][tok]
  float sm = v0 + v1;
  #pragma unroll
  for (int m = 1; m < 64; m <<= 1) sm += __shfl_xor(sm, m);
  float mu = sm * (1.f / 128.f);
  float d0 = v0 - mu, d1 = v1 - mu;
  float sq = d0 * d0 + d1 * d1;
  #pragma unroll
  for (int m = 1; m < 64; m <<= 1) sq += __shfl_xor(sq, m);
  float rs = rsqrtf(sq * (1.f / 128.f) + 1e-6f);
  float kn0 = d0 * rs * gam[2 * lane]     + bet[2 * lane];
  float kn1 = d1 * rs * gam[2 * lane + 1] + bet[2 * lane + 1];
  float o0 = kn0, o1 = kn1;
  if (lane < 32) {
    float c  = cosb[tok * 64 + 2 * lane];
    float sn = sinb[tok * 64 + 2 * lane];
    o0 = kn0 * c - kn1 * sn;
    o1 = kn1 * c + kn0 * sn;
  }
  Kout[tok * 128 + 2 * lane]     = f2bf(o0);
  Kout[tok * 128 + 2 * lane + 1] = f2bf(o1);
}

// ---------------- legacy Q-GEMM (fallback path when workspace is small) ----------------
template<bool AGLDS>
__global__ __launch_bounds__(256) void qgemm(const void* __restrict__ Aptr,
    const u16* __restrict__ BT, const float* __restrict__ cosb,
    const float* __restrict__ sinb, u16* __restrict__ Qout){
  constexpr int K = 1536, N = 8192;
  __shared__ u16 As[2 * 128 * 32];   // [kc][128][32] unpadded (glds / packed stores)
  __shared__ u16 Bs[2 * 128 * 32];
  const int tid = threadIdx.x, wave = tid >> 6, lane = tid & 63;
  const int row = lane & 15, quad = lane >> 4;
  const int wm = (wave >> 1) * 64, wn = (wave & 1) * 64;
  const int m0 = blockIdx.y * 128, n0 = blockIdx.x * 128;

  const f32x4 zero = {0.f, 0.f, 0.f, 0.f};
  f32x4 acc[4][4];
  #pragma unroll
  for (int mt = 0; mt < 4; ++mt)
    #pragma unroll
    for (int nt = 0; nt < 4; ++nt) acc[mt][nt] = zero;

  for (int k0 = 0; k0 < K; k0 += 64) {
    #pragma unroll
    for (int c = 0; c < 4; ++c) {            // B: 16 chunks (1024B), 4/wave
      int chunk = wave * 4 + c;
      int kc = chunk >> 3, rg = chunk & 7;
      int r = rg * 16 + (lane >> 2), col = kc * 32 + (lane & 3) * 8;
      glds16(BT + (size_t)(n0 + r) * K + k0 + col, (void*)&Bs[chunk * 512]);
    }
    if (AGLDS) {
      #pragma unroll
      for (int c = 0; c < 4; ++c) {
        int chunk = wave * 4 + c;
        int kc = chunk >> 3, rg = chunk & 7;
        int r = rg * 16 + (lane >> 2), col = kc * 32 + (lane & 3) * 8;
        glds16((const u16*)Aptr + (size_t)(m0 + r) * K + k0 + col, (void*)&As[chunk * 512]);
      }
    } else {
      #pragma unroll
      for (int c = 0; c < 4; ++c) {          // A: f32 load + pack, 128x64
        int idx = tid + c * 256;
        int r = idx >> 3, kf = (idx & 7) * 8;
        const float4* ap = (const float4*)((const float*)Aptr + (size_t)(m0 + r) * K + k0 + kf);
        float4 f0 = ap[0], f1 = ap[1];
        u32 w[4] = { pk2bf(f0.x, f0.y), pk2bf(f0.z, f0.w), pk2bf(f1.x, f1.y), pk2bf(f1.z, f1.w) };
        *(uint4*)&As[(kf >> 5) * 4096 + r * 32 + (kf & 31)] = *(const uint4*)w;
      }
    }
    __syncthreads();
    #pragma unroll
    for (int kk = 0; kk < 2; ++kk) {
      bf16x8 af[4], bfr[4];
      #pragma unroll
      for (int mt = 0; mt < 4; ++mt) af[mt]  = *(const bf16x8*)&As[kk * 4096 + (wm + mt * 16 + row) * 32 + quad * 8];
      #pragma unroll
      for (int nt = 0; nt < 4; ++nt) bfr[nt] = *(const bf16x8*)&Bs[kk * 4096 + (wn + nt * 16 + row) * 32 + quad * 8];
      #pragma unroll
      for (int mt = 0; mt < 4; ++mt)
        #pragma unroll
        for (int nt = 0; nt < 4; ++nt)
          acc[mt][nt] = __builtin_amdgcn_mfma_f32_16x16x32_bf16(af[mt], bfr[nt], acc[mt][nt], 0, 0, 0);
    }
    __syncthreads();
  }

  const bool roped = (wn == 0);
  #pragma unroll
  for (int mt = 0; mt < 4; ++mt)
    #pragma unroll
    for (int nt = 0; nt < 4; ++nt)
      #pragma unroll
      for (int r = 0; r < 4; ++r) {
        int rr = m0 + wm + mt * 16 + quad * 4 + r;
        int cc = n0 + wn + nt * 16 + row;
        float v = acc[mt][nt][r];
        float o = v;
        if (roped) {
          int hd = (wn + nt * 16 + row) & 127;
          float c = cosb[rr * 64 + hd];
          float s = sinb[rr * 64 + hd];
          float vo = __shfl_xor(v, 1);
          o = (cc & 1) ? (v * c + vo * s) : (v * c - vo * s);
        }
        Qout[(size_t)rr * N + cc] = f2bf(o);
      }
}

// ---------------- Q-GEMM v6 (proven best, 79us): 256x256, 4-phase counted-vmcnt, lockstep ----------------
__global__ __launch_bounds__(512, 2) void qgemm256v6(const u16* __restrict__ A,
    const u16* __restrict__ BT, const float* __restrict__ cosb,
    const float* __restrict__ sinb, u16* __restrict__ Qout){
  constexpr int K = 1536, N = 8192, NT = 24;
  __shared__ __align__(16) u16 As[2 * 2 * 256 * 32];   // 64 KiB: [d][kk][row][32]
  __shared__ __align__(16) u16 Bs[2 * 2 * 256 * 32];   // 64 KiB
  const int tid = threadIdx.x, wave = tid >> 6, lane = tid & 63;
  const int lrow = lane & 15, quad = lane >> 4;
  const int wm2 = wave >> 2, wn4 = wave & 3;           // 2M x 4N waves; wave tile 128x64

  const int flat = blockIdx.y * 32 + blockIdx.x;       // 256 blocks = 256 CUs
  const int n_t  = (flat & 7) * 4 + (flat >> 6);
  const int m_t  = (flat >> 3) & 7;
  const int m0 = m_t * 256, n0 = n_t * 256;

  const int scolb = ((tid & 3) << 4) ^ (((tid >> 3) & 1) << 5) ^ (((tid >> 4) & 1) << 4);
  const int scole = scolb >> 1;
  const int srow  = tid >> 2;
  const u16* sa0 = A  + (size_t)(m0 +       srow) * K + scole;
  const u16* sa1 = A  + (size_t)(m0 + 128 + srow) * K + scole;
  const u16* sb0 = BT + (size_t)(n0 +       srow) * K + scole;
  const u16* sb1 = BT + (size_t)(n0 + 128 + srow) * K + scole;

  auto stagept = [&](int t, int h){                    // one half-point: 4 glds16/thread
    const int off = t * 64 + h * 32;
    u16* la = (u16*)As + (size_t)((t & 1) * 2 + h) * 8192 + wave * 512;
    u16* lb = (u16*)Bs + (size_t)((t & 1) * 2 + h) * 8192 + wave * 512;
    glds16(sa0 + off, (void*)la);
    glds16(sa1 + off, (void*)(la + 4096));
    glds16(sb0 + off, (void*)lb);
    glds16(sb1 + off, (void*)(lb + 4096));
  };

  const int swzr = ((lrow & 2) << 4) | ((lrow & 4) << 2);
  const int aoff = (wm2 * 128 + lrow) * 64 + ((quad * 16) ^ swzr);   // + mt*1024
  const int boff = (wn4 * 64  + lrow) * 64 + ((quad * 16) ^ swzr);   // + nt*1024

  const f32x4 zero = {0.f, 0.f, 0.f, 0.f};
  f32x4 acc[8][4];
  #pragma unroll
  for (int mt = 0; mt < 8; ++mt)
    #pragma unroll
    for (int nt = 0; nt < 4; ++nt) acc[mt][nt] = zero;

  stagept(0, 0); stagept(0, 1); stagept(1, 0);

  for (int t = 0; t < NT; ++t) {
    const int d = t & 1;
    const bool last = (t == NT - 1);
    const char* A0 = (const char*)As + d * 32768;
    const char* B0 = (const char*)Bs + d * 32768;
    const char* A1 = A0 + 16384;
    const char* B1 = B0 + 16384;
    bf16x8 af[4], bfr[4];

    // P1: kk=0, acc rows 0-3
    if (!last) { asm volatile("s_waitcnt vmcnt(8)" ::: "memory"); }
    else       { asm volatile("s_waitcnt vmcnt(4)" ::: "memory"); }
    hard_barrier();
    #pragma unroll
    for (int j = 0; j < 4; ++j) af[j]  = *(const bf16x8*)(A0 + aoff + j * 1024);
    #pragma unroll
    for (int j = 0; j < 4; ++j) bfr[j] = *(const bf16x8*)(B0 + boff + j * 1024);
    if (t + 1 < NT) stagept(t + 1, 1);
    asm volatile("s_waitcnt lgkmcnt(0)" ::: "memory");
    __builtin_amdgcn_sched_barrier(0);
    __builtin_amdgcn_s_setprio(1);
    #pragma unroll
    for (int j = 0; j < 4; ++j)
      #pragma unroll
      for (int nt = 0; nt < 4; ++nt)
        acc[j][nt] = __builtin_amdgcn_mfma_f32_16x16x32_bf16(af[j], bfr[nt], acc[j][nt], 0, 0, 0);
    __builtin_amdgcn_s_setprio(0);
    hard_barrier();

    // P2: kk=0, acc rows 4-7
    #pragma unroll
    for (int j = 0; j < 4; ++j) af[j] = *(const bf16x8*)(A0 + aoff + (4 + j) * 1024);
    asm volatile("s_waitcnt lgkmcnt(0)" ::: "memory");
    __builtin_amdgcn_sched_barrier(0);
    __builtin_amdgcn_s_setprio(1);
    #pragma unroll
    for (int j = 0; j < 4; ++j)
      #pragma unroll
      for (int nt = 0; nt < 4; ++nt)
        acc[4 + j][nt] = __builtin_amdgcn_mfma_f32_16x16x32_bf16(af[j], bfr[nt], acc[4 + j][nt], 0, 0, 0);
    __builtin_amdgcn_s_setprio(0);
    hard_barrier();

    // P3: kk=1, acc rows 0-3
    if (!last) { asm volatile("s_waitcnt vmcnt(8)" ::: "memory"); }
    else       { asm volatile("s_waitcnt vmcnt(0)" ::: "memory"); }
    hard_barrier();
    #pragma unroll
    for (int j = 0; j < 4; ++j) af[j]  = *(const bf16x8*)(A1 + aoff + j * 1024);
    #pragma unroll
    for (int j = 0; j < 4; ++j) bfr[j] = *(const bf16x8*)(B1 + boff + j * 1024);
    if (t + 2 < NT) stagept(t + 2, 0);
    asm volatile("s_waitcnt lgkmcnt(0)" ::: "memory");
    __builtin_amdgcn_sched_barrier(0);
    __builtin_amdgcn_s_setprio(1);
    #pragma unroll
    for (int j = 0; j < 4; ++j)
      #pragma unroll
      for (int nt = 0; nt < 4; ++nt)
        acc[j][nt] = __builtin_amdgcn_mfma_f32_16x16x32_bf16(af[j], bfr[nt], acc[j][nt], 0, 0, 0);
    __builtin_amdgcn_s_setprio(0);
    hard_barrier();

    // P4: kk=1, acc rows 4-7
    #pragma unroll
    for (int j = 0; j < 4; ++j) af[j] = *(const bf16x8*)(A1 + aoff + (4 + j) * 1024);
    asm volatile("s_waitcnt lgkmcnt(0)" ::: "memory");
    __builtin_amdgcn_sched_barrier(0);
    __builtin_amdgcn_s_setprio(1);
    #pragma unroll
    for (int j = 0; j < 4; ++j)
      #pragma unroll
      for (int nt = 0; nt < 4; ++nt)
        acc[4 + j][nt] = __builtin_amdgcn_mfma_f32_16x16x32_bf16(af[j], bfr[nt], acc[4 + j][nt], 0, 0, 0);
    __builtin_amdgcn_s_setprio(0);
    hard_barrier();
  }

  const bool roped = !(wn4 & 1);
  #pragma unroll
  for (int mt = 0; mt < 8; ++mt)
    #pragma unroll
    for (int nt = 0; nt < 4; ++nt)
      #pragma unroll
      for (int r = 0; r < 4; ++r) {
        int rr = m0 + wm2 * 128 + mt * 16 + quad * 4 + r;
        int cc = n0 + wn4 * 64 + nt * 16 + lrow;
        float v = acc[mt][nt][r];
        float o = v;
        if (roped) {
          int hd = nt * 16 + lrow;                 // < 64
          float c = cosb[rr * 64 + hd];
          float s = sinb[rr * 64 + hd];
          float vo = __shfl_xor(v, 1);
          o = (cc & 1) ? (v * c + vo * s) : (v * c - vo * s);
        }
        Qout[(size_t)rr * N + cc] = f2bf(o);
      }
}

// ---------------- fused scores v2: kt-merge x2 (64q x 256k x 32h per block, 8 waves) ----------------
// Halves global Q traffic (256->128 MB) and per-CU Q LDS-staging vs the 4-wave kernel, with
// IDENTICAL per-wave structure (bfr[4][4] own-k-slice, sacc[2][4], same MFMA loop).
// Grid 256 = 2b x 16qt x 4kp x 2hs; 8 waves = 2q(wm 0/32) x 4k(wn 0/64/128/192).
// LDS: K 256x128 (64 KB, consumed into regs) then reused as Q pair double-buffer; Ws 8 KB.
// XCD remap: all 8 (kp,hs)-siblings of one (b,qt) land on one XCD (shared Q slice L2-resident).
__global__ __launch_bounds__(512) void attn_kernel2(const u16* __restrict__ Q,
    const u16* __restrict__ Kb, const float* __restrict__ WT, float* __restrict__ out){
  const int l = (blockIdx.x & 7) * 32 + (blockIdx.x >> 3);   // bijective 8x32 transpose
  const int hs = l & 1, kp = (l >> 1) & 3, qt = (l >> 3) & 15, b = (l >> 7) & 1;
  const int q0 = qt * 64, k0 = kp * 256;

  const int tid = threadIdx.x, wave = tid >> 6, lane = tid & 63;
  const int row = lane & 15, quad = lane >> 4;
  const int wm = (wave >> 2) * 32;            // q offset (0/32)
  const int wn = (wave & 3) * 64;             // k offset within block's 256 (0/64/128/192)

  __shared__ u16 Sh[2][16384];                // 64 KB: first holds K 256x128, then Q dbuf
  __shared__ float Ws[32 * 64];               // 8 KB: [h_local][q_local]
  u16* KS = &Sh[0][0];                        // flat view over both buffers

  // stage K 256x128 into KS as [r][128]: 64 chunks (1024 B = 4 rows), 8/wave
  #pragma unroll
  for (int c = 0; c < 8; ++c) {
    int g = wave * 8 + c;
    int rr = g * 4 + (lane >> 4), col = (lane & 15) * 8;
    glds16(Kb + (size_t)(b * 1024 + k0 + rr) * 128 + col, (void*)&KS[g * 512]);
  }
  if (tid < 256) {
    int hl = tid >> 3, qq = (tid & 7) * 8;
    const float* srcw = WT + (size_t)(hs * 32 + hl) * 2048 + b * 1024 + q0 + qq;
    *(float4*)&Ws[hl * 64 + qq]     = *(const float4*)srcw;
    *(float4*)&Ws[hl * 64 + qq + 4] = *(const float4*)(srcw + 4);
  }
  __syncthreads();

  bf16x8 bfr[4][4];                           // this wave's 64-k slice, h-invariant
  #pragma unroll
  for (int ks = 0; ks < 4; ++ks)
    #pragma unroll
    for (int nt = 0; nt < 4; ++nt)
      bfr[ks][nt] = *(const bf16x8*)&KS[(wn + nt * 16 + row) * 128 + ks * 32 + quad * 8];
  __syncthreads();                            // all waves done reading K before Q overwrites

  const u16* Qbase = Q + (size_t)(b * 1024 + q0) * 8192;
  auto stage = [&](int half, int pairIdx){    // stage 2 heads (32 KB): 32 chunks, 4/wave
    int h0 = hs * 32 + pairIdx * 2;
    #pragma unroll
    for (int c = 0; c < 4; ++c) {
      int g = wave * 4 + c;
      int hsub = g >> 4, rem = g & 15;
      int kc = rem >> 2, rg = rem & 3;
      glds16(Qbase + (size_t)(rg * 16 + (lane >> 2)) * 8192 + (h0 + hsub) * 128 + kc * 32 + (lane & 3) * 8,
             (void*)&Sh[half][hsub * 8192 + rem * 512]);
    }
  };

  const f32x4 zero = {0.f, 0.f, 0.f, 0.f};
  f32x4 sacc[2][4];
  #pragma unroll
  for (int mt = 0; mt < 2; ++mt)
    #pragma unroll
    for (int nt = 0; nt < 4; ++nt) sacc[mt][nt] = zero;

  stage(0, 0);                                // prefetch pair 0
  for (int hp = 0; hp < 16; ++hp) {
    __syncthreads();                          // drains pair hp's glds (in shadow for hp>=1)
    if (hp < 15) stage((hp + 1) & 1, hp + 1); // prefetch next pair before compute
    const u16* S = Sh[hp & 1];
    #pragma unroll
    for (int hsub = 0; hsub < 2; ++hsub) {
      f32x4 lg[2][4];
      #pragma unroll
      for (int mt = 0; mt < 2; ++mt)
        #pragma unroll
        for (int nt = 0; nt < 4; ++nt) lg[mt][nt] = zero;
      #pragma unroll
      for (int ks = 0; ks < 4; ++ks) {
        bf16x8 af0 = *(const bf16x8*)&S[hsub * 8192 + ks * 2048 + (wm +      row) * 32 + quad * 8];
        bf16x8 af1 = *(const bf16x8*)&S[hsub * 8192 + ks * 2048 + (wm + 16 + row) * 32 + quad * 8];
        #pragma unroll
        for (int nt = 0; nt < 4; ++nt) {
          lg[0][nt] = __builtin_amdgcn_mfma_f32_16x16x32_bf16(af0, bfr[ks][nt], lg[0][nt], 0, 0, 0);
          lg[1][nt] = __builtin_amdgcn_mfma_f32_16x16x32_bf16(af1, bfr[ks][nt], lg[1][nt], 0, 0, 0);
        }
      }
      int hl = hp * 2 + hsub;
      f32x4 w0 = *(const f32x4*)&Ws[hl * 64 + wm +      quad * 4];
      f32x4 w1 = *(const f32x4*)&Ws[hl * 64 + wm + 16 + quad * 4];
      #pragma unroll
      for (int nt = 0; nt < 4; ++nt)
        #pragma unroll
        for (int r = 0; r < 4; ++r) {
          sacc[0][nt][r] += w0[r] * fmaxf(lg[0][nt][r], 0.f);
          sacc[1][nt][r] += w1[r] * fmaxf(lg[1][nt][r], 0.f);
        }
    }
  }

  const float scale = 0.088388347648318447f;  // 128^-0.5
  #pragma unroll
  for (int mt = 0; mt < 2; ++mt)
    #pragma unroll
    for (int nt = 0; nt < 4; ++nt)
      #pragma unroll
      for (int r = 0; r < 4; ++r) {
        int qq = q0 + wm + mt * 16 + quad * 4 + r;
        int kk = k0 + wn + nt * 16 + row;
        unsafeAtomicAdd(&out[((size_t)b << 20) + (size_t)qq * 1024 + kk], scale * sacc[mt][nt][r]);
      }
}

extern "C" void kernel_launch(void* const* d_in, const int* in_sizes, int n_in,
                              void* d_out, int out_size, void* d_ws, size_t ws_size,
                              hipStream_t stream) {
  const float* x    = (const float*)d_in[0];   // [2048][7168]
  const float* qr   = (const float*)d_in[1];   // [2048][1536]
  const float* cosb = (const float*)d_in[2];   // [2048][64]
  const float* sinb = (const float*)d_in[3];   // [2048][64]
  const float* wq   = (const float*)d_in[4];   // [1536][8192]
  const float* wk   = (const float*)d_in[5];   // [7168][128]
  const float* wp   = (const float*)d_in[6];   // [7168][64]
  const float* gam  = (const float*)d_in[7];   // [128]
  const float* bet  = (const float*)d_in[8];   // [128]
  float* out = (float*)d_out;                  // [2][1024][1024] f32

  char* ws = (char*)d_ws;
  float* P    = (float*)(ws + 0);          // [16][2048][192] f32 = 25,165,824 B (proj phase)
  u16*   wqT  = (u16*)(ws + 0);            // [8192][1536] bf16 (after reduce; same region)
  u16*   wkwpT= (u16*)(ws + 25165824);     // [192][7168] bf16 = 2,752,512 B
  float* WT   = (float*)(ws + 27918336);   // [64][2048] f32 = 524,288 B (transposed W)
  u16*   Kbf  = (u16*)(ws + 28442624);     // [2048][128] bf16 = 524,288 B
  u16*   Qbf  = (u16*)(ws + 28966912);     // [2048][8192] bf16 = 33,554,432 B -> 62,521,344
  const size_t QRB_OFF = 62521344;
  u16*   qrb  = (u16*)(ws + QRB_OFF);      // [2048][1536] bf16 = 6,291,456 B -> 68,812,800
  const bool big_ws = (ws_size >= (size_t)68812800);

  (void)in_sizes; (void)n_in;

  hipMemsetAsync(d_out, 0, (size_t)out_size * 4, stream);

  transpose_f32_bf16_v<<<dim3(2, 112), 256, 0, stream>>>(wk, wkwpT,              7168, 128);
  transpose_f32_bf16_v<<<dim3(1, 112), 256, 0, stream>>>(wp, wkwpT + 128 * 7168, 7168, 64);

  proj_splitk<<<dim3(16, 32), 256, 0, stream>>>(x, wkwpT, P);
  reduce_lnrope<<<2048, 64, 0, stream>>>(P, cosb, sinb, gam, bet, Kbf, WT);

  transpose_f32_bf16_v<<<dim3(128, 24), 256, 0, stream>>>(wq, wqT, 1536, 8192);

  if (big_ws) {
    cvt_f32_bf16<<<1536, 256, 0, stream>>>(qr, qrb);
    qgemm256v6<<<dim3(32, 8), 512, 0, stream>>>(qrb, wqT, cosb, sinb, Qbf);
  } else {
    qgemm<false><<<dim3(64, 16), 256, 0, stream>>>(qr, wqT, cosb, sinb, Qbf);
  }

  attn_kernel2<<<256, 512, 0, stream>>>(Qbf, Kbf, WT, out);
}